// Round 16
// baseline (71.339 us; speedup 1.0000x reference)
//
#include <hip/hip_runtime.h>

// CircleLoss, B=8192, D=128, fp32 in, scalar fp32 out.
// DIAGNOSTIC ROUND: champion R14 pipeline, but simlse launched with
// gridDim.z=3 -- duplicates do identical work and write identical values to
// the same partS addresses (deterministic, exact). This stretches simlse's
// dispatch above the harness's 41us poison-fills so rocprof finally shows
// its counters (all prior profiles of sub-40us kernels were masked).

#define B_N 8192
#define D_K 128
#define MARGIN 0.25f
#define M2 (MARGIN * MARGIN)
#define GAMMA 256.0f

#define BM 128          // rows per block (A panel)
#define BN 64           // cols per subtile
#define NCH 16          // column chunks (grid.x)
#define CPB (B_N / NCH) // 512 columns per chunk
#define NSUB (CPB / BN) // 8 subtiles per chunk
#define NROWBLK 32      // rowfin blocks

typedef __attribute__((ext_vector_type(8))) short short8;
typedef __attribute__((ext_vector_type(4))) float f32x4;

__device__ __forceinline__ unsigned short f2bf(float x) {
  // round-to-nearest-even fp32 -> bf16
  unsigned u = __float_as_uint(x);
  u += 0x7FFFu + ((u >> 16) & 1u);
  return (unsigned short)(u >> 16);
}

__device__ __forceinline__ void gload_lds16(const void* gsrc, void* ldst) {
  // async 16B/lane global->LDS; LDS dest is wave-uniform base + lane*16
  __builtin_amdgcn_global_load_lds(
      (const __attribute__((address_space(1))) void*)gsrc,
      (__attribute__((address_space(3))) void*)ldst, 16, 0, 0);
}

// ------- kernel 1: L2-normalize rows -> bf16, plus diagonal dot -------
__global__ __launch_bounds__(256) void norm_diag_kernel(
    const float* __restrict__ a, const float* __restrict__ b,
    unsigned short* __restrict__ abf, unsigned short* __restrict__ bbf,
    float* __restrict__ diag) {
  int wave = threadIdx.x >> 6, lane = threadIdx.x & 63;
  int r = blockIdx.x * 4 + wave;  // 0..B_N-1
  int half = lane >> 5, l32 = lane & 31;
  const float* src = half ? b : a;
  unsigned short* dst = half ? bbf : abf;

  float4 v = ((const float4*)(src + (size_t)r * D_K))[l32];
  float ss = v.x * v.x + v.y * v.y + v.z * v.z + v.w * v.w;
  #pragma unroll
  for (int m = 16; m >= 1; m >>= 1) ss += __shfl_xor(ss, m);  // within half
  float inv = 1.0f / fmaxf(sqrtf(ss), 1e-12f);
  float n0 = v.x * inv, n1 = v.y * inv, n2 = v.z * inv, n3 = v.w * inv;

  ushort4 o = {f2bf(n0), f2bf(n1), f2bf(n2), f2bf(n3)};
  ((ushort4*)(dst + (size_t)r * D_K))[l32] = o;

  // diagonal dot: pair with same l32 in the other half
  float d = n0 * __shfl_xor(n0, 32) + n1 * __shfl_xor(n1, 32) +
            n2 * __shfl_xor(n2, 32) + n3 * __shfl_xor(n3, 32);
  #pragma unroll
  for (int m = 16; m >= 1; m >>= 1) d += __shfl_xor(d, m);
  if (lane == 0) diag[r] = d;
}

// ---------- kernel 2: fused sim GEMM (bf16 MFMA) + neg-LSE partials ----------
// grid = (NCH, B_N/BM, 3): z-duplicates are byte-identical (diagnostic).
// block = 256 (4 waves; each wave owns a 32x64 output strip as 2x4 fragments
// of 16x16). C = A_n * B_n^T via mfma_f32_16x16x32_bf16.
// dbuf = 2 x 16KB LDS; A staged once via both buffers, hoisted to 32 VGPRs.
// XOR-swizzled 16B granules (pre-swizzled global source), reads slot^(row&7).
// Epilogue accumulates sum(exp(logit_neg)-1) with uniform __any skip.
__global__ __launch_bounds__(256, 2) void simlse_kernel(
    const unsigned short* __restrict__ abf, const unsigned short* __restrict__ bbf,
    float* __restrict__ partS) {
  __shared__ __align__(16) unsigned short L[2][BN * D_K];  // 2 x 16 KB

  const int tid = threadIdx.x;
  const int wave = tid >> 6, lane = tid & 63;
  const int r16 = lane & 15, kq = lane >> 4;
  const int rowBase = blockIdx.y * BM;
  const int chunk = blockIdx.x;

  // per-lane staging source offsets (element units) within a 64x128 tile
  int stageOff[4];
  #pragma unroll
  for (int it = 0; it < 4; ++it) {
    int g = it * 256 + tid;
    int row = g >> 4, sl = g & 15;
    stageOff[it] = row * D_K + (sl ^ (row & 7)) * 8;
  }

  // stage A rows [0,64) -> L[0], rows [64,128) -> L[1] (swizzled)
  #pragma unroll
  for (int half = 0; half < 2; ++half) {
    const unsigned short* srcA = abf + (size_t)(rowBase + half * 64) * D_K;
    #pragma unroll
    for (int it = 0; it < 4; ++it)
      gload_lds16(srcA + stageOff[it], &L[half][(it * 256 + wave * 64) * 8]);
  }
  __syncthreads();  // vmcnt drained: A ready

  // hoist A-fragments into registers (reused by all subtiles)
  short8 af[2][4];  // [mi][ks]
  #pragma unroll
  for (int mi = 0; mi < 2; ++mi) {
    int row = wave * 32 + mi * 16 + r16;  // 0..127
    const unsigned short* Abuf = L[row >> 6];
    int lrow = row & 63;
    #pragma unroll
    for (int ks = 0; ks < 4; ++ks) {
      int slot = (ks * 4 + kq) ^ (lrow & 7);
      af[mi][ks] = *(const short8*)&Abuf[lrow * D_K + slot * 8];
    }
  }
  __syncthreads();  // all waves done reading A -> buffers reusable

  // stage B subtile 0 -> L[0], subtile 1 -> L[1]
  #pragma unroll
  for (int h = 0; h < 2; ++h) {
    const unsigned short* srcB = bbf + (size_t)(chunk * CPB + h * BN) * D_K;
    #pragma unroll
    for (int it = 0; it < 4; ++it)
      gload_lds16(srcB + stageOff[it], &L[h][(it * 256 + wave * 64) * 8]);
  }
  __syncthreads();  // B0, B1 ready

  float Ssum[2][4];  // [mi][reg] per-row running sum of (exp(logit_neg)-1)
  #pragma unroll
  for (int mi = 0; mi < 2; ++mi)
    #pragma unroll
    for (int r = 0; r < 4; ++r) Ssum[mi][r] = 0.0f;

  #pragma unroll 2
  for (int st = 0; st < NSUB; ++st) {
    const unsigned short* cb = L[st & 1];  // current B buffer

    f32x4 acc[2][4];
    const f32x4 z4 = {0.f, 0.f, 0.f, 0.f};
    #pragma unroll
    for (int mi = 0; mi < 2; ++mi)
      #pragma unroll
      for (int ni = 0; ni < 4; ++ni) acc[mi][ni] = z4;

    #pragma unroll
    for (int ks = 0; ks < 4; ++ks) {
      short8 bf[4];
      #pragma unroll
      for (int ni = 0; ni < 4; ++ni) {
        int row = ni * 16 + r16;  // 0..63
        int slot = (ks * 4 + kq) ^ (row & 7);
        bf[ni] = *(const short8*)&cb[row * D_K + slot * 8];
      }
      #pragma unroll
      for (int mi = 0; mi < 2; ++mi)
        #pragma unroll
        for (int ni = 0; ni < 4; ++ni)
          acc[mi][ni] = __builtin_amdgcn_mfma_f32_16x16x32_bf16(
              af[mi][ks], bf[ni], acc[mi][ni], 0, 0, 0);
    }

    // epilogue: logit = (s>m) ? GAMMA*(s^2-m^2) : 0; accumulate exp(logit)-1.
    #pragma unroll
    for (int mi = 0; mi < 2; ++mi)
      #pragma unroll
      for (int ni = 0; ni < 4; ++ni) {
        f32x4 v = acc[mi][ni];
        float mx = fmaxf(fmaxf(v[0], v[1]), fmaxf(v[2], v[3]));
        if (__any(mx > MARGIN)) {
          #pragma unroll
          for (int r = 0; r < 4; ++r) {
            float s = v[r];
            float t = fmaf(s, s, -M2);
            float z = (s > MARGIN) ? GAMMA * t : 0.0f;
            Ssum[mi][r] += __expf(z) - 1.0f;  // exactly 0 when z==0
          }
        }
      }

    __syncthreads();  // ends reads of cb; drains next buffer's prefetch

    if (st + 2 < NSUB) {  // prefetch subtile st+2 into the buffer just freed
      const unsigned short* srcB =
          bbf + (size_t)(chunk * CPB + (st + 2) * BN) * D_K;
      unsigned short* dstB = (unsigned short*)L[st & 1];
      #pragma unroll
      for (int it = 0; it < 4; ++it)
        gload_lds16(srcB + stageOff[it], &dstB[(it * 256 + wave * 64) * 8]);
    }
  }

  // reduce over the 16 column-lanes (same kq group); all z-duplicates write
  // IDENTICAL values to the same addresses (deterministic, exact).
  #pragma unroll
  for (int mi = 0; mi < 2; ++mi)
    #pragma unroll
    for (int r = 0; r < 4; ++r) {
      float v = Ssum[mi][r];
      v += __shfl_xor(v, 1);
      v += __shfl_xor(v, 2);
      v += __shfl_xor(v, 4);
      v += __shfl_xor(v, 8);
      if (r16 == 0)
        partS[(size_t)chunk * B_N + rowBase + wave * 32 + mi * 16 + kq * 4 + r] = v;
    }
}

// ------- kernel 3: per-row finalize + per-block partial sum -------
__global__ __launch_bounds__(256) void rowfin_kernel(
    const float* __restrict__ partS, const float* __restrict__ diag,
    float* __restrict__ bpart) {
  __shared__ float red[4];
  int tid = threadIdx.x, lane = tid & 63, wid = tid >> 6;
  int i = blockIdx.x * 256 + tid;
  float S = 0.0f;
  #pragma unroll
  for (int c = 0; c < NCH; ++c) S += partS[(size_t)c * B_N + i];
  float sd = diag[i];
  float zd = (sd > MARGIN) ? GAMMA * fmaf(sd, sd, -M2) : 0.0f;
  float ed = __expf(zd);
  // sum over off-diagonal of exp(logit_neg) = B + sum(e-1 over all) - e_diag
  float lneg = __logf((float)B_N + S - ed);
  float lpos = -GAMMA * fmaxf((1.0f - MARGIN) - sd, 0.0f) * (sd - MARGIN);
  float x = lpos + lneg;
  float acc = fmaxf(x, 0.0f) + log1pf(__expf(-fabsf(x)));  // softplus
  #pragma unroll
  for (int m = 32; m >= 1; m >>= 1) acc += __shfl_xor(acc, m);
  if (lane == 0) red[wid] = acc;
  __syncthreads();
  if (tid == 0) bpart[blockIdx.x] = red[0] + red[1] + red[2] + red[3];
}

// ---------------- kernel 4: mean over 32 block partials ----------------
__global__ __launch_bounds__(64) void mean_kernel(
    const float* __restrict__ bpart, float* __restrict__ out) {
  int lane = threadIdx.x;
  float v = (lane < 32) ? bpart[lane] : 0.0f;
  #pragma unroll
  for (int m = 32; m >= 1; m >>= 1) v += __shfl_xor(v, m);
  if (lane == 0) out[0] = v * (1.0f / B_N);
}

extern "C" void kernel_launch(void* const* d_in, const int* in_sizes, int n_in,
                              void* d_out, int out_size, void* d_ws, size_t ws_size,
                              hipStream_t stream) {
  const float* a = (const float*)d_in[0];
  const float* b = (const float*)d_in[1];
  float* out = (float*)d_out;

  char* w = (char*)d_ws;
  unsigned short* abf = (unsigned short*)w;                              // 2 MB
  unsigned short* bbf = (unsigned short*)(w + (size_t)B_N * D_K * 2);    // 2 MB
  float* partS = (float*)(w + (size_t)B_N * D_K * 4);                    // 512 KB
  float* diag = partS + (size_t)NCH * B_N;                               // 32 KB
  float* bpart = diag + B_N;                                             // 128 B

  norm_diag_kernel<<<B_N / 4, 256, 0, stream>>>(a, b, abf, bbf, diag);
  // z=3: diagnostic amplification (identical work, identical writes)
  simlse_kernel<<<dim3(NCH, B_N / BM, 3), 256, 0, stream>>>(abf, bbf, partS);
  rowfin_kernel<<<NROWBLK, 256, 0, stream>>>(partS, diag, bpart);
  mean_kernel<<<1, 64, 0, stream>>>(bpart, out);
}

// Round 17
// 42.356 us; speedup vs baseline: 1.6843x; 1.6843x over previous
//
#include <hip/hip_runtime.h>

// CircleLoss, B=8192, D=128, fp32 in, scalar fp32 out.
// Pipeline: (1) normalize->bf16 + fused diagonal dot, (2) fused bf16-MFMA
// sim GEMM + masked-LSE partials (BN=64 dbuf; NCH=32 -> 2048 short blocks:
// deep per-CU queue keeps resident blocks phase-staggered, measured 23.4us
// per cohort at 12 blocks/CU vs 30.5 at exactly 4; setprio on MFMA cluster),
// (3) rowfin, (4) mean.

#define B_N 8192
#define D_K 128
#define MARGIN 0.25f
#define M2 (MARGIN * MARGIN)
#define GAMMA 256.0f

#define BM 128          // rows per block (A panel)
#define BN 64           // cols per subtile
#define NCH 32          // column chunks (grid.x)
#define CPB (B_N / NCH) // 256 columns per chunk
#define NSUB (CPB / BN) // 4 subtiles per chunk
#define NROWBLK 32      // rowfin blocks

typedef __attribute__((ext_vector_type(8))) short short8;
typedef __attribute__((ext_vector_type(4))) float f32x4;

__device__ __forceinline__ unsigned short f2bf(float x) {
  // round-to-nearest-even fp32 -> bf16
  unsigned u = __float_as_uint(x);
  u += 0x7FFFu + ((u >> 16) & 1u);
  return (unsigned short)(u >> 16);
}

__device__ __forceinline__ void gload_lds16(const void* gsrc, void* ldst) {
  // async 16B/lane global->LDS; LDS dest is wave-uniform base + lane*16
  __builtin_amdgcn_global_load_lds(
      (const __attribute__((address_space(1))) void*)gsrc,
      (__attribute__((address_space(3))) void*)ldst, 16, 0, 0);
}

// ------- kernel 1: L2-normalize rows -> bf16, plus diagonal dot -------
// One wave per row index r: lanes 0-31 handle a[r], lanes 32-63 handle b[r]
// (float4 each). After normalize, cross-half shfl gives diag[r]=dot(a_n,b_n).
__global__ __launch_bounds__(256) void norm_diag_kernel(
    const float* __restrict__ a, const float* __restrict__ b,
    unsigned short* __restrict__ abf, unsigned short* __restrict__ bbf,
    float* __restrict__ diag) {
  int wave = threadIdx.x >> 6, lane = threadIdx.x & 63;
  int r = blockIdx.x * 4 + wave;  // 0..B_N-1
  int half = lane >> 5, l32 = lane & 31;
  const float* src = half ? b : a;
  unsigned short* dst = half ? bbf : abf;

  float4 v = ((const float4*)(src + (size_t)r * D_K))[l32];
  float ss = v.x * v.x + v.y * v.y + v.z * v.z + v.w * v.w;
  #pragma unroll
  for (int m = 16; m >= 1; m >>= 1) ss += __shfl_xor(ss, m);  // within half
  float inv = 1.0f / fmaxf(sqrtf(ss), 1e-12f);
  float n0 = v.x * inv, n1 = v.y * inv, n2 = v.z * inv, n3 = v.w * inv;

  ushort4 o = {f2bf(n0), f2bf(n1), f2bf(n2), f2bf(n3)};
  ((ushort4*)(dst + (size_t)r * D_K))[l32] = o;

  // diagonal dot: pair with same l32 in the other half
  float d = n0 * __shfl_xor(n0, 32) + n1 * __shfl_xor(n1, 32) +
            n2 * __shfl_xor(n2, 32) + n3 * __shfl_xor(n3, 32);
  #pragma unroll
  for (int m = 16; m >= 1; m >>= 1) d += __shfl_xor(d, m);
  if (lane == 0) diag[r] = d;
}

// ---------- kernel 2: fused sim GEMM (bf16 MFMA) + neg-LSE partials ----------
// grid = (NCH, B_N/BM) = (32,64) = 2048 blocks, block = 256 (4 waves; each
// wave owns a 32x64 output strip as 2x4 fragments of 16x16).
// C = A_n * B_n^T via mfma_f32_16x16x32_bf16. dbuf = 2x16KB LDS; 4 resident
// blocks/CU (LDS cap) + 4 queued: replacement keeps residents phase-staggered
// (R16 diagnostic: 12 queued blocks/CU ran 23.4us/cohort vs 30.5 at exactly
// 4 -- the stagger, not occupancy, was the gain).
// A staged once via both buffers, hoisted to 32 VGPRs. XOR-swizzled 16B
// granules (pre-swizzled global source), reads slot = s ^ (row&7).
// Epilogue accumulates sum(exp(logit_neg)-1) with uniform __any skip.
__global__ __launch_bounds__(256, 2) void simlse_kernel(
    const unsigned short* __restrict__ abf, const unsigned short* __restrict__ bbf,
    float* __restrict__ partS) {
  __shared__ __align__(16) unsigned short L[2][BN * D_K];  // 2 x 16 KB

  const int tid = threadIdx.x;
  const int wave = tid >> 6, lane = tid & 63;
  const int r16 = lane & 15, kq = lane >> 4;
  const int rowBase = blockIdx.y * BM;
  const int chunk = blockIdx.x;

  // per-lane staging source offsets (element units) within a 64x128 tile:
  // granule g = it*256 + tid, row = g>>4 (0..63), slot pre-swizzled.
  int stageOff[4];
  #pragma unroll
  for (int it = 0; it < 4; ++it) {
    int g = it * 256 + tid;
    int row = g >> 4, sl = g & 15;
    stageOff[it] = row * D_K + (sl ^ (row & 7)) * 8;
  }

  // stage A rows [0,64) -> L[0], rows [64,128) -> L[1] (swizzled)
  #pragma unroll
  for (int half = 0; half < 2; ++half) {
    const unsigned short* srcA = abf + (size_t)(rowBase + half * 64) * D_K;
    #pragma unroll
    for (int it = 0; it < 4; ++it)
      gload_lds16(srcA + stageOff[it], &L[half][(it * 256 + wave * 64) * 8]);
  }
  __syncthreads();  // vmcnt drained: A ready

  // hoist A-fragments into registers (reused by all subtiles)
  short8 af[2][4];  // [mi][ks]
  #pragma unroll
  for (int mi = 0; mi < 2; ++mi) {
    int row = wave * 32 + mi * 16 + r16;  // 0..127
    const unsigned short* Abuf = L[row >> 6];
    int lrow = row & 63;
    #pragma unroll
    for (int ks = 0; ks < 4; ++ks) {
      int slot = (ks * 4 + kq) ^ (lrow & 7);
      af[mi][ks] = *(const short8*)&Abuf[lrow * D_K + slot * 8];
    }
  }
  __syncthreads();  // all waves done reading A -> buffers reusable

  // stage B subtile 0 -> L[0], subtile 1 -> L[1]
  #pragma unroll
  for (int h = 0; h < 2; ++h) {
    const unsigned short* srcB = bbf + (size_t)(chunk * CPB + h * BN) * D_K;
    #pragma unroll
    for (int it = 0; it < 4; ++it)
      gload_lds16(srcB + stageOff[it], &L[h][(it * 256 + wave * 64) * 8]);
  }
  __syncthreads();  // B0, B1 ready

  float Ssum[2][4];  // [mi][reg] per-row running sum of (exp(logit_neg)-1)
  #pragma unroll
  for (int mi = 0; mi < 2; ++mi)
    #pragma unroll
    for (int r = 0; r < 4; ++r) Ssum[mi][r] = 0.0f;

  #pragma unroll 2
  for (int st = 0; st < NSUB; ++st) {
    const unsigned short* cb = L[st & 1];  // current B buffer

    f32x4 acc[2][4];
    const f32x4 z4 = {0.f, 0.f, 0.f, 0.f};
    #pragma unroll
    for (int mi = 0; mi < 2; ++mi)
      #pragma unroll
      for (int ni = 0; ni < 4; ++ni) acc[mi][ni] = z4;

    __builtin_amdgcn_s_setprio(1);
    #pragma unroll
    for (int ks = 0; ks < 4; ++ks) {
      short8 bf[4];
      #pragma unroll
      for (int ni = 0; ni < 4; ++ni) {
        int row = ni * 16 + r16;  // 0..63
        int slot = (ks * 4 + kq) ^ (row & 7);
        bf[ni] = *(const short8*)&cb[row * D_K + slot * 8];
      }
      #pragma unroll
      for (int mi = 0; mi < 2; ++mi)
        #pragma unroll
        for (int ni = 0; ni < 4; ++ni)
          acc[mi][ni] = __builtin_amdgcn_mfma_f32_16x16x32_bf16(
              af[mi][ks], bf[ni], acc[mi][ni], 0, 0, 0);
    }
    __builtin_amdgcn_s_setprio(0);

    // epilogue: logit = (s>m) ? GAMMA*(s^2-m^2) : 0; accumulate exp(logit)-1.
    // For unit-normal embeddings P(s>m) ~ 0.2%, so most reg-quads skip.
    #pragma unroll
    for (int mi = 0; mi < 2; ++mi)
      #pragma unroll
      for (int ni = 0; ni < 4; ++ni) {
        f32x4 v = acc[mi][ni];
        float mx = fmaxf(fmaxf(v[0], v[1]), fmaxf(v[2], v[3]));
        if (__any(mx > MARGIN)) {
          #pragma unroll
          for (int r = 0; r < 4; ++r) {
            float s = v[r];
            float t = fmaf(s, s, -M2);
            float z = (s > MARGIN) ? GAMMA * t : 0.0f;
            Ssum[mi][r] += __expf(z) - 1.0f;  // exactly 0 when z==0
          }
        }
      }

    __syncthreads();  // ends reads of cb; drains next buffer's prefetch

    if (st + 2 < NSUB) {  // prefetch subtile st+2 into the buffer just freed
      const unsigned short* srcB =
          bbf + (size_t)(chunk * CPB + (st + 2) * BN) * D_K;
      unsigned short* dstB = (unsigned short*)L[st & 1];
      #pragma unroll
      for (int it = 0; it < 4; ++it)
        gload_lds16(srcB + stageOff[it], &dstB[(it * 256 + wave * 64) * 8]);
    }
  }

  // each wave owns its 32 rows across the FULL chunk width -> reduce over the
  // 16 column-lanes (same kq group) and write partS directly.
  #pragma unroll
  for (int mi = 0; mi < 2; ++mi)
    #pragma unroll
    for (int r = 0; r < 4; ++r) {
      float v = Ssum[mi][r];
      v += __shfl_xor(v, 1);
      v += __shfl_xor(v, 2);
      v += __shfl_xor(v, 4);
      v += __shfl_xor(v, 8);
      if (r16 == 0)
        partS[(size_t)chunk * B_N + rowBase + wave * 32 + mi * 16 + kq * 4 + r] = v;
    }
}

// ------- kernel 3: per-row finalize + per-block partial sum -------
__global__ __launch_bounds__(256) void rowfin_kernel(
    const float* __restrict__ partS, const float* __restrict__ diag,
    float* __restrict__ bpart) {
  __shared__ float red[4];
  int tid = threadIdx.x, lane = tid & 63, wid = tid >> 6;
  int i = blockIdx.x * 256 + tid;
  float S = 0.0f;
  #pragma unroll
  for (int c = 0; c < NCH; ++c) S += partS[(size_t)c * B_N + i];
  float sd = diag[i];
  float zd = (sd > MARGIN) ? GAMMA * fmaf(sd, sd, -M2) : 0.0f;
  float ed = __expf(zd);
  // sum over off-diagonal of exp(logit_neg) = B + sum(e-1 over all) - e_diag
  float lneg = __logf((float)B_N + S - ed);
  float lpos = -GAMMA * fmaxf((1.0f - MARGIN) - sd, 0.0f) * (sd - MARGIN);
  float x = lpos + lneg;
  float acc = fmaxf(x, 0.0f) + log1pf(__expf(-fabsf(x)));  // softplus
  #pragma unroll
  for (int m = 32; m >= 1; m >>= 1) acc += __shfl_xor(acc, m);
  if (lane == 0) red[wid] = acc;
  __syncthreads();
  if (tid == 0) bpart[blockIdx.x] = red[0] + red[1] + red[2] + red[3];
}

// ---------------- kernel 4: mean over 32 block partials ----------------
__global__ __launch_bounds__(64) void mean_kernel(
    const float* __restrict__ bpart, float* __restrict__ out) {
  int lane = threadIdx.x;
  float v = (lane < 32) ? bpart[lane] : 0.0f;
  #pragma unroll
  for (int m = 32; m >= 1; m >>= 1) v += __shfl_xor(v, m);
  if (lane == 0) out[0] = v * (1.0f / B_N);
}

extern "C" void kernel_launch(void* const* d_in, const int* in_sizes, int n_in,
                              void* d_out, int out_size, void* d_ws, size_t ws_size,
                              hipStream_t stream) {
  const float* a = (const float*)d_in[0];
  const float* b = (const float*)d_in[1];
  float* out = (float*)d_out;

  char* w = (char*)d_ws;
  unsigned short* abf = (unsigned short*)w;                              // 2 MB
  unsigned short* bbf = (unsigned short*)(w + (size_t)B_N * D_K * 2);    // 2 MB
  float* partS = (float*)(w + (size_t)B_N * D_K * 4);                    // 1 MB
  float* diag = partS + (size_t)NCH * B_N;                               // 32 KB
  float* bpart = diag + B_N;                                             // 128 B

  norm_diag_kernel<<<B_N / 4, 256, 0, stream>>>(a, b, abf, bbf, diag);
  simlse_kernel<<<dim3(NCH, B_N / BM), 256, 0, stream>>>(abf, bbf, partS);
  rowfin_kernel<<<NROWBLK, 256, 0, stream>>>(partS, diag, bpart);
  mean_kernel<<<1, 64, 0, stream>>>(bpart, out);
}

// Round 18
// 37.682 us; speedup vs baseline: 1.8932x; 1.1240x over previous
//
#include <hip/hip_runtime.h>

// CircleLoss, B=8192, D=128, fp32 in, scalar fp32 out.
// Pipeline: (1) normalize->bf16 + fused diagonal dot, (2) fused bf16-MFMA
// sim GEMM + masked-LSE partials (BN=64 dbuf, A-frags in regs, BIJECTIVE
// XCD-AWARE BLOCK SWIZZLE: each XCD owns 2 chunks x 64 row-blocks so its L2
// working set is 2MB A + 256KB B instead of all 4MB), (3) rowfin, (4) mean.

#define B_N 8192
#define D_K 128
#define MARGIN 0.25f
#define M2 (MARGIN * MARGIN)
#define GAMMA 256.0f

#define BM 128          // rows per block (A panel)
#define BN 64           // cols per subtile
#define NCH 16          // column chunks
#define CPB (B_N / NCH) // 512 columns per chunk
#define NSUB (CPB / BN) // 8 subtiles per chunk
#define NROWBLK 32      // rowfin blocks

typedef __attribute__((ext_vector_type(8))) short short8;
typedef __attribute__((ext_vector_type(4))) float f32x4;

__device__ __forceinline__ unsigned short f2bf(float x) {
  // round-to-nearest-even fp32 -> bf16
  unsigned u = __float_as_uint(x);
  u += 0x7FFFu + ((u >> 16) & 1u);
  return (unsigned short)(u >> 16);
}

__device__ __forceinline__ void gload_lds16(const void* gsrc, void* ldst) {
  // async 16B/lane global->LDS; LDS dest is wave-uniform base + lane*16
  __builtin_amdgcn_global_load_lds(
      (const __attribute__((address_space(1))) void*)gsrc,
      (__attribute__((address_space(3))) void*)ldst, 16, 0, 0);
}

// ------- kernel 1: L2-normalize rows -> bf16, plus diagonal dot -------
// One wave per row index r: lanes 0-31 handle a[r], lanes 32-63 handle b[r]
// (float4 each). After normalize, cross-half shfl gives diag[r]=dot(a_n,b_n).
__global__ __launch_bounds__(256) void norm_diag_kernel(
    const float* __restrict__ a, const float* __restrict__ b,
    unsigned short* __restrict__ abf, unsigned short* __restrict__ bbf,
    float* __restrict__ diag) {
  int wave = threadIdx.x >> 6, lane = threadIdx.x & 63;
  int r = blockIdx.x * 4 + wave;  // 0..B_N-1
  int half = lane >> 5, l32 = lane & 31;
  const float* src = half ? b : a;
  unsigned short* dst = half ? bbf : abf;

  float4 v = ((const float4*)(src + (size_t)r * D_K))[l32];
  float ss = v.x * v.x + v.y * v.y + v.z * v.z + v.w * v.w;
  #pragma unroll
  for (int m = 16; m >= 1; m >>= 1) ss += __shfl_xor(ss, m);  // within half
  float inv = 1.0f / fmaxf(sqrtf(ss), 1e-12f);
  float n0 = v.x * inv, n1 = v.y * inv, n2 = v.z * inv, n3 = v.w * inv;

  ushort4 o = {f2bf(n0), f2bf(n1), f2bf(n2), f2bf(n3)};
  ((ushort4*)(dst + (size_t)r * D_K))[l32] = o;

  // diagonal dot: pair with same l32 in the other half
  float d = n0 * __shfl_xor(n0, 32) + n1 * __shfl_xor(n1, 32) +
            n2 * __shfl_xor(n2, 32) + n3 * __shfl_xor(n3, 32);
  #pragma unroll
  for (int m = 16; m >= 1; m >>= 1) d += __shfl_xor(d, m);
  if (lane == 0) diag[r] = d;
}

// ---------- kernel 2: fused sim GEMM (bf16 MFMA) + neg-LSE partials ----------
// grid = 1024 blocks (1D). XCD swizzle: dispatch round-robins consecutive
// blockIdx across the 8 XCDs, so xcd=bid&7, lid=bid>>3 gives each XCD a
// contiguous slice {2 chunks x 64 row-blocks}. Per-XCD L2 working set drops
// from (all A + all B = 4MB, thrashing the 4MB L2 + spilling to L3) to
// (2MB A + 256KB B). Without this, tile re-reads (~167MB) run at L3 speed --
// the hidden pole behind the 37us plateau (FETCH_SIZE never saw it: L3
// absorbs, HBM idle).
// block = 256 (4 waves; each wave owns a 32x64 output strip as 2x4 frags of
// 16x16). C = A_n * B_n^T via mfma_f32_16x16x32_bf16. dbuf = 2x16KB LDS.
// A staged once via both buffers, hoisted to 32 VGPRs. XOR-swizzled 16B
// granules (pre-swizzled global source), reads slot = s ^ (row&7).
// Epilogue accumulates sum(exp(logit_neg)-1) with uniform __any skip.
__global__ __launch_bounds__(256, 2) void simlse_kernel(
    const unsigned short* __restrict__ abf, const unsigned short* __restrict__ bbf,
    float* __restrict__ partS) {
  __shared__ __align__(16) unsigned short L[2][BN * D_K];  // 2 x 16 KB

  const int tid = threadIdx.x;
  const int wave = tid >> 6, lane = tid & 63;
  const int r16 = lane & 15, kq = lane >> 4;

  // XCD-aware bijective swizzle (nwg=1024 = 8 XCDs x 128)
  const int bid = blockIdx.x;
  const int xcd = bid & 7, lid = bid >> 3;   // lid 0..127
  const int chunk = xcd * 2 + (lid >> 6);    // 0..15
  const int rowBase = (lid & 63) * BM;       // 0..8064

  // per-lane staging source offsets (element units) within a 64x128 tile:
  // granule g = it*256 + tid, row = g>>4 (0..63), slot pre-swizzled.
  int stageOff[4];
  #pragma unroll
  for (int it = 0; it < 4; ++it) {
    int g = it * 256 + tid;
    int row = g >> 4, sl = g & 15;
    stageOff[it] = row * D_K + (sl ^ (row & 7)) * 8;
  }

  // stage A rows [0,64) -> L[0], rows [64,128) -> L[1] (swizzled)
  #pragma unroll
  for (int half = 0; half < 2; ++half) {
    const unsigned short* srcA = abf + (size_t)(rowBase + half * 64) * D_K;
    #pragma unroll
    for (int it = 0; it < 4; ++it)
      gload_lds16(srcA + stageOff[it], &L[half][(it * 256 + wave * 64) * 8]);
  }
  __syncthreads();  // vmcnt drained: A ready

  // hoist A-fragments into registers (reused by all subtiles)
  short8 af[2][4];  // [mi][ks]
  #pragma unroll
  for (int mi = 0; mi < 2; ++mi) {
    int row = wave * 32 + mi * 16 + r16;  // 0..127
    const unsigned short* Abuf = L[row >> 6];
    int lrow = row & 63;
    #pragma unroll
    for (int ks = 0; ks < 4; ++ks) {
      int slot = (ks * 4 + kq) ^ (lrow & 7);
      af[mi][ks] = *(const short8*)&Abuf[lrow * D_K + slot * 8];
    }
  }
  __syncthreads();  // all waves done reading A -> buffers reusable

  // stage B subtile 0 -> L[0], subtile 1 -> L[1]
  #pragma unroll
  for (int h = 0; h < 2; ++h) {
    const unsigned short* srcB = bbf + (size_t)(chunk * CPB + h * BN) * D_K;
    #pragma unroll
    for (int it = 0; it < 4; ++it)
      gload_lds16(srcB + stageOff[it], &L[h][(it * 256 + wave * 64) * 8]);
  }
  __syncthreads();  // B0, B1 ready

  float Ssum[2][4];  // [mi][reg] per-row running sum of (exp(logit_neg)-1)
  #pragma unroll
  for (int mi = 0; mi < 2; ++mi)
    #pragma unroll
    for (int r = 0; r < 4; ++r) Ssum[mi][r] = 0.0f;

  #pragma unroll 2
  for (int st = 0; st < NSUB; ++st) {
    const unsigned short* cb = L[st & 1];  // current B buffer

    f32x4 acc[2][4];
    const f32x4 z4 = {0.f, 0.f, 0.f, 0.f};
    #pragma unroll
    for (int mi = 0; mi < 2; ++mi)
      #pragma unroll
      for (int ni = 0; ni < 4; ++ni) acc[mi][ni] = z4;

    #pragma unroll
    for (int ks = 0; ks < 4; ++ks) {
      short8 bf[4];
      #pragma unroll
      for (int ni = 0; ni < 4; ++ni) {
        int row = ni * 16 + r16;  // 0..63
        int slot = (ks * 4 + kq) ^ (row & 7);
        bf[ni] = *(const short8*)&cb[row * D_K + slot * 8];
      }
      #pragma unroll
      for (int mi = 0; mi < 2; ++mi)
        #pragma unroll
        for (int ni = 0; ni < 4; ++ni)
          acc[mi][ni] = __builtin_amdgcn_mfma_f32_16x16x32_bf16(
              af[mi][ks], bf[ni], acc[mi][ni], 0, 0, 0);
    }

    // epilogue: logit = (s>m) ? GAMMA*(s^2-m^2) : 0; accumulate exp(logit)-1.
    // For unit-normal embeddings P(s>m) ~ 0.2%, so most reg-quads skip.
    #pragma unroll
    for (int mi = 0; mi < 2; ++mi)
      #pragma unroll
      for (int ni = 0; ni < 4; ++ni) {
        f32x4 v = acc[mi][ni];
        float mx = fmaxf(fmaxf(v[0], v[1]), fmaxf(v[2], v[3]));
        if (__any(mx > MARGIN)) {
          #pragma unroll
          for (int r = 0; r < 4; ++r) {
            float s = v[r];
            float t = fmaf(s, s, -M2);
            float z = (s > MARGIN) ? GAMMA * t : 0.0f;
            Ssum[mi][r] += __expf(z) - 1.0f;  // exactly 0 when z==0
          }
        }
      }

    __syncthreads();  // ends reads of cb; drains next buffer's prefetch

    if (st + 2 < NSUB) {  // prefetch subtile st+2 into the buffer just freed
      const unsigned short* srcB =
          bbf + (size_t)(chunk * CPB + (st + 2) * BN) * D_K;
      unsigned short* dstB = (unsigned short*)L[st & 1];
      #pragma unroll
      for (int it = 0; it < 4; ++it)
        gload_lds16(srcB + stageOff[it], &dstB[(it * 256 + wave * 64) * 8]);
    }
  }

  // each wave owns its 32 rows across the FULL chunk width -> reduce over the
  // 16 column-lanes (same kq group) and write partS directly.
  #pragma unroll
  for (int mi = 0; mi < 2; ++mi)
    #pragma unroll
    for (int r = 0; r < 4; ++r) {
      float v = Ssum[mi][r];
      v += __shfl_xor(v, 1);
      v += __shfl_xor(v, 2);
      v += __shfl_xor(v, 4);
      v += __shfl_xor(v, 8);
      if (r16 == 0)
        partS[(size_t)chunk * B_N + rowBase + wave * 32 + mi * 16 + kq * 4 + r] = v;
    }
}

// ------- kernel 3: per-row finalize + per-block partial sum -------
__global__ __launch_bounds__(256) void rowfin_kernel(
    const float* __restrict__ partS, const float* __restrict__ diag,
    float* __restrict__ bpart) {
  __shared__ float red[4];
  int tid = threadIdx.x, lane = tid & 63, wid = tid >> 6;
  int i = blockIdx.x * 256 + tid;
  float S = 0.0f;
  #pragma unroll
  for (int c = 0; c < NCH; ++c) S += partS[(size_t)c * B_N + i];
  float sd = diag[i];
  float zd = (sd > MARGIN) ? GAMMA * fmaf(sd, sd, -M2) : 0.0f;
  float ed = __expf(zd);
  // sum over off-diagonal of exp(logit_neg) = B + sum(e-1 over all) - e_diag
  float lneg = __logf((float)B_N + S - ed);
  float lpos = -GAMMA * fmaxf((1.0f - MARGIN) - sd, 0.0f) * (sd - MARGIN);
  float x = lpos + lneg;
  float acc = fmaxf(x, 0.0f) + log1pf(__expf(-fabsf(x)));  // softplus
  #pragma unroll
  for (int m = 32; m >= 1; m >>= 1) acc += __shfl_xor(acc, m);
  if (lane == 0) red[wid] = acc;
  __syncthreads();
  if (tid == 0) bpart[blockIdx.x] = red[0] + red[1] + red[2] + red[3];
}

// ---------------- kernel 4: mean over 32 block partials ----------------
__global__ __launch_bounds__(64) void mean_kernel(
    const float* __restrict__ bpart, float* __restrict__ out) {
  int lane = threadIdx.x;
  float v = (lane < 32) ? bpart[lane] : 0.0f;
  #pragma unroll
  for (int m = 32; m >= 1; m >>= 1) v += __shfl_xor(v, m);
  if (lane == 0) out[0] = v * (1.0f / B_N);
}

extern "C" void kernel_launch(void* const* d_in, const int* in_sizes, int n_in,
                              void* d_out, int out_size, void* d_ws, size_t ws_size,
                              hipStream_t stream) {
  const float* a = (const float*)d_in[0];
  const float* b = (const float*)d_in[1];
  float* out = (float*)d_out;

  char* w = (char*)d_ws;
  unsigned short* abf = (unsigned short*)w;                              // 2 MB
  unsigned short* bbf = (unsigned short*)(w + (size_t)B_N * D_K * 2);    // 2 MB
  float* partS = (float*)(w + (size_t)B_N * D_K * 4);                    // 512 KB
  float* diag = partS + (size_t)NCH * B_N;                               // 32 KB
  float* bpart = diag + B_N;                                             // 128 B

  norm_diag_kernel<<<B_N / 4, 256, 0, stream>>>(a, b, abf, bbf, diag);
  simlse_kernel<<<NCH * (B_N / BM), 256, 0, stream>>>(abf, bbf, partS);
  rowfin_kernel<<<NROWBLK, 256, 0, stream>>>(partS, diag, bpart);
  mean_kernel<<<1, 64, 0, stream>>>(bpart, out);
}